// Round 7
// baseline (93.560 us; speedup 1.0000x reference)
//
#include <hip/hip_runtime.h>

// Problem constants (from reference setup_inputs)
constexpr int cB = 32, cC = 6, cT = 64;
constexpr int cK = 8, cN = 128;
constexpr int cS = 32, cP = 64;
constexpr int NSEG_PAD = cK * cN;     // 1024 slots; n==127 are pads
constexpr int NCL  = cS * cP;         // 2048 centerline points per batch
constexpr int G = 8;                  // blocks per (b,c); 8 points per block
constexpr int PPW = 2;                // points per wave (register-blocked)
constexpr int NIT = NSEG_PAD / 64;    // 16 iterations per lane
constexpr float F_EPS = 1e-6f;
constexpr float F_THRESHOLD = 0.5f;

// 1536 blocks (6/CU), 4 waves/block, 2 points/wave -> 6 waves/SIMD for
// latency hiding (R4/R6 showed 3 waves/SIMD leaves VALUBusy at ~35%).
__global__ __launch_bounds__(256, 6) void offroad_kernel(
    const float* __restrict__ points,         // (B, C, T, 2)
    const float* __restrict__ road_boundary,  // (B, K, N, 2)
    const float* __restrict__ centerlines,    // (B, S, P, 2)
    float* __restrict__ out)                  // (B, C), pre-zeroed
{
    const int blk  = blockIdx.x;         // 0 .. B*C*G-1
    const int g    = blk & (G - 1);
    const int bc   = blk >> 3;           // b*C + c
    const int b    = bc / cC;
    const int lane = threadIdx.x & 63;
    const int wave = threadIdx.x >> 6;

    const float2* __restrict__ rb2 =
        (const float2*)(road_boundary + (size_t)b * cK * cN * 2);
    const float4* __restrict__ cl4 =
        (const float4*)(centerlines + (size_t)b * NCL * 2);

    // 2 consecutive points for this wave (wave-uniform -> scalar loads)
    const int t0 = (g << 3) | (wave << 1);   // in [0, 64)
    const float* pb = points + (((size_t)bc) * cT + t0) * 2;
    float px[PPW], py[PPW];
    #pragma unroll
    for (int p = 0; p < PPW; ++p) { px[p] = pb[2 * p]; py[p] = pb[2 * p + 1]; }

    // ---- Fused + pipelined: segment distance + centerline argmin ----
    float min_d2[PPW], best_d2[PPW];
    int   best_i[PPW];
    #pragma unroll
    for (int p = 0; p < PPW; ++p) {
        min_d2[p] = 3.4e38f; best_d2[p] = 3.4e38f; best_i[p] = 0x7fffffff;
    }

    int s = lane;
    // prologue loads (pad lanes n==127: s1=s -> d=0 -> endpoint distance,
    // >= adjacent real segment's distance -> min unaffected)
    float2 a  = rb2[s];
    float2 nx = rb2[s + (((s & (cN - 1)) < cN - 1) ? 1 : 0)];
    float4 cp = cl4[s];

    #pragma unroll 4
    for (int i = 0; i < NIT; ++i) {
        const float2 ac = a;  const float2 nxc = nx;  const float4 cpc = cp;
        const int    sc = s;
        s += 64;
        if (i < NIT - 1) {    // prefetch next iteration
            a  = rb2[s];
            nx = rb2[s + (((s & (cN - 1)) < cN - 1) ? 1 : 0)];
            cp = cl4[s];
        }

        const float dx = nxc.x - ac.x, dy = nxc.y - ac.y;
        const float inv_e2 = __builtin_amdgcn_rcpf(dx * dx + dy * dy + F_EPS);
        const int ia = 2 * sc;

        #pragma unroll
        for (int p = 0; p < PPW; ++p) {
            // point-to-segment distance
            float v1x = px[p] - ac.x, v1y = py[p] - ac.y;
            float proj = (v1x * dx + v1y * dy) * inv_e2;
            proj = fminf(fmaxf(proj, 0.0f), 1.0f);
            float ex = v1x - dx * proj;
            float ey = v1y - dy * proj;
            min_d2[p] = fminf(min_d2[p], ex * ex + ey * ey);

            // centerline argmin (first-index tie-break, matches jnp.argmin)
            float dxa = px[p] - cpc.x, dya = py[p] - cpc.y;
            float d2a = dxa * dxa + dya * dya;
            float dxb = px[p] - cpc.z, dyb = py[p] - cpc.w;
            float d2b = dxb * dxb + dyb * dyb;
            float dmin = d2a; int imin = ia;
            if (d2b < d2a) { dmin = d2b; imin = ia + 1; }  // lower idx on tie
            if (dmin < best_d2[p] ||
                (dmin == best_d2[p] && imin < best_i[p])) {
                best_d2[p] = dmin; best_i[p] = imin;
            }
        }
    }

    // argmin butterfly across 64 lanes (tie -> lower index)
    #pragma unroll
    for (int off = 1; off <= 32; off <<= 1) {
        #pragma unroll
        for (int p = 0; p < PPW; ++p) {
            float od2 = __shfl_xor(best_d2[p], off);
            int   oi  = __shfl_xor(best_i[p], off);
            if (od2 < best_d2[p] || (od2 == best_d2[p] && oi < best_i[p])) {
                best_d2[p] = od2; best_i[p] = oi;
            }
        }
    }

    // closest centerline point per point (lane-uniform broadcast loads)
    const float2* __restrict__ cl2 = (const float2*)cl4;
    float dax[PPW], day[PPW];
    #pragma unroll
    for (int p = 0; p < PPW; ++p) {
        float2 cc = cl2[best_i[p]];
        dax[p] = cc.x - px[p]; day[p] = cc.y - py[p];   // da = a2 - a1
    }

    // ---- Segment intersection, pipelined, division-free ----
    // t,u in [0,1] with t=ct/w, u=cu/w, w=dadb+EPS:
    //   0<=t<=1  <=>  ct*w >= 0  &&  ct*w <= w*w   (multiply by w^2 > 0)
    int hit[PPW] = {0, 0};
    s = lane;
    a  = rb2[s];
    nx = rb2[s + (((s & (cN - 1)) < cN - 1) ? 1 : 0)];

    #pragma unroll 4
    for (int i = 0; i < NIT; ++i) {
        const float2 ac = a;  const float2 nxc = nx;
        const int    sc = s;
        s += 64;
        if (i < NIT - 1) {    // prefetch next iteration
            a  = rb2[s];
            nx = rb2[s + (((s & (cN - 1)) < cN - 1) ? 1 : 0)];
        }

        const float dbx = nxc.x - ac.x, dby = nxc.y - ac.y;  // db
        const int valid = ((sc & (cN - 1)) < cN - 1) ? 1 : 0;

        #pragma unroll
        for (int p = 0; p < PPW; ++p) {
            float dpx = px[p] - ac.x, dpy = py[p] - ac.y;    // dp = a1 - b1
            float w  = dax[p] * dby - day[p] * dbx + F_EPS;  // cross(da,db)+EPS
            float w2 = w * w;
            float ct = (dax[p] * dpy - day[p] * dpx) * w;    // cross(da,dp)*w
            float cu = (dbx * dpy - dby * dpx) * w;          // cross(db,dp)*w
            bool inb = (ct >= 0.0f) & (ct <= w2) & (cu >= 0.0f) & (cu <= w2);
            hit[p] |= valid & (int)inb;
        }
    }

    // ---- reduce min_d2 / hit across 64 lanes ----
    #pragma unroll
    for (int off = 1; off <= 32; off <<= 1) {
        #pragma unroll
        for (int p = 0; p < PPW; ++p) {
            min_d2[p] = fminf(min_d2[p], __shfl_xor(min_d2[p], off));
            hit[p]   |= __shfl_xor(hit[p], off);
        }
    }

    // ---- final loss for this wave's points, one atomic per wave ----
    float total = 0.0f;
    #pragma unroll
    for (int p = 0; p < PPW; ++p) {
        float md = sqrtf(min_d2[p]);
        float sd = hit[p] ? md : -md;               // inside -> negative
        total += fmaxf(sd + F_THRESHOLD, 0.0f);
    }
    if (lane == 0)
        atomicAdd(&out[bc], total);
}

extern "C" void kernel_launch(void* const* d_in, const int* in_sizes, int n_in,
                              void* d_out, int out_size, void* d_ws, size_t ws_size,
                              hipStream_t stream) {
    const float* points      = (const float*)d_in[0];
    const float* boundary    = (const float*)d_in[1];
    const float* centerlines = (const float*)d_in[2];
    float* out = (float*)d_out;
    hipMemsetAsync(out, 0, (size_t)out_size * sizeof(float), stream);
    offroad_kernel<<<cB * cC * G, 256, 0, stream>>>(points, boundary, centerlines, out);
}

// Round 10
// 82.175 us; speedup vs baseline: 1.1386x; 1.1386x over previous
//
#include <hip/hip_runtime.h>

// Problem constants (from reference setup_inputs)
constexpr int cB = 32, cC = 6, cT = 64;
constexpr int cK = 8, cN = 128;
constexpr int cS = 32, cP = 64;
constexpr int NSEG_PAD = cK * cN;     // 1024 slots; n==127 are pads
constexpr int NCL  = cS * cP;         // 2048 centerline points per batch
constexpr int G = 4;                  // blocks per (b,c); 16 points per block
constexpr int PPW = 4;                // points per wave (register-blocked)
constexpr int NIT = NSEG_PAD / 64;    // 16 iterations per lane
constexpr float F_EPS = 1e-6f;
constexpr float F_THRESHOLD = 0.5f;

// 768 blocks (3/CU), 4 waves/block, 4 pts/wave. Centerline pass first, then
// ONE fused segment pass doing distance+intersection (they share v1 = p-a).
// Neighbor vertex rb2[s+1] comes from __shfl_down(a,1); lane 63 takes the
// next iteration's lane-0 prefetch (even i) or is a pad slot (odd i).
// R8/R9 bug fixed here: the prefetch register `an` is now written back to
// the loop-carried `a` (R8/R9 silently re-processed slots 0..63 16 times).
__global__ __launch_bounds__(256) void offroad_kernel(
    const float* __restrict__ points,         // (B, C, T, 2)
    const float* __restrict__ road_boundary,  // (B, K, N, 2)
    const float* __restrict__ centerlines,    // (B, S, P, 2)
    float* __restrict__ out)                  // (B, C), pre-zeroed
{
    const int blk  = blockIdx.x;         // 0 .. B*C*G-1
    const int g    = blk & (G - 1);
    const int bc   = blk >> 2;           // b*C + c
    const int b    = bc / cC;
    const int lane = threadIdx.x & 63;
    const int wave = threadIdx.x >> 6;

    const float2* __restrict__ rb2 =
        (const float2*)(road_boundary + (size_t)b * cK * cN * 2);
    const float4* __restrict__ cl4 =
        (const float4*)(centerlines + (size_t)b * NCL * 2);

    // 4 consecutive points for this wave (wave-uniform -> scalar loads)
    const int t0 = (g << 4) | (wave << 2);   // in [0, 64)
    const float* pb = points + (((size_t)bc) * cT + t0) * 2;
    float px[PPW], py[PPW];
    #pragma unroll
    for (int p = 0; p < PPW; ++p) { px[p] = pb[2 * p]; py[p] = pb[2 * p + 1]; }

    // ---- Pass 1: centerline argmin (first-index tie-break) ----
    float best_d2[PPW];
    int   best_i[PPW];
    #pragma unroll
    for (int p = 0; p < PPW; ++p) { best_d2[p] = 3.4e38f; best_i[p] = 0x7fffffff; }

    {
        int s = lane;
        float4 cp = cl4[s];
        #pragma unroll 4
        for (int i = 0; i < NIT; ++i) {
            const float4 cpc = cp;
            const int sc = s;
            s += 64;
            if (i < NIT - 1) cp = cl4[s];    // prefetch (loop-carried)
            const int ia = 2 * sc;
            #pragma unroll
            for (int p = 0; p < PPW; ++p) {
                float dxa = px[p] - cpc.x, dya = py[p] - cpc.y;
                float d2a = dxa * dxa + dya * dya;
                float dxb = px[p] - cpc.z, dyb = py[p] - cpc.w;
                float d2b = dxb * dxb + dyb * dyb;
                float dmin = d2a; int imin = ia;
                if (d2b < d2a) { dmin = d2b; imin = ia + 1; }  // lower idx on tie
                if (dmin < best_d2[p] ||
                    (dmin == best_d2[p] && imin < best_i[p])) {
                    best_d2[p] = dmin; best_i[p] = imin;
                }
            }
        }
    }
    // argmin butterfly across 64 lanes (tie -> lower index)
    #pragma unroll
    for (int off = 1; off <= 32; off <<= 1) {
        #pragma unroll
        for (int p = 0; p < PPW; ++p) {
            float od2 = __shfl_xor(best_d2[p], off);
            int   oi  = __shfl_xor(best_i[p], off);
            if (od2 < best_d2[p] || (od2 == best_d2[p] && oi < best_i[p])) {
                best_d2[p] = od2; best_i[p] = oi;
            }
        }
    }
    // closest centerline point per point (lane-uniform broadcast loads)
    const float2* __restrict__ cl2 = (const float2*)cl4;
    float dax[PPW], day[PPW];
    #pragma unroll
    for (int p = 0; p < PPW; ++p) {
        float2 cc = cl2[best_i[p]];
        dax[p] = cc.x - px[p]; day[p] = cc.y - py[p];   // da = a2 - a1
    }

    // ---- Pass 2: fused segment distance + intersection, 1 load/iter ----
    float min_d2[PPW];
    int   hit[PPW];
    #pragma unroll
    for (int p = 0; p < PPW; ++p) { min_d2[p] = 3.4e38f; hit[p] = 0; }

    {
        int s = lane;
        float2 a = rb2[s];
        #pragma unroll 2
        for (int i = 0; i < NIT; ++i) {
            const float2 ac = a;
            s += 64;
            float2 an = ac;                  // epilogue dummy (i=15 is a pad
            if (i < NIT - 1) an = rb2[s];    // row for lane 63 -> never used)

            // ALL lanes execute every shuffle (wave-uniform), then select:
            //   lanes 0..62: neighbor = lane+1's a
            //   lane 63, i even: next iteration's lane-0 a
            //   lane 63, i odd : pad slot (s & 127 == 127) -> nx = a (d=0)
            float sd_x = __shfl_down(ac.x, 1);
            float sd_y = __shfl_down(ac.y, 1);
            float b0x  = __shfl(an.x, 0);
            float b0y  = __shfl(an.y, 0);
            const bool last = (lane == 63);
            const bool odd  = (i & 1) != 0;
            float nx_x = last ? (odd ? ac.x : b0x) : sd_x;
            float nx_y = last ? (odd ? ac.y : b0y) : sd_y;
            const int valid = (last && odd) ? 0 : 1;

            a = an;   // <<< the R8/R9 fix: carry the prefetch forward

            const float dx = nx_x - ac.x, dy = nx_y - ac.y;
            const float inv_e2 =
                __builtin_amdgcn_rcpf(dx * dx + dy * dy + F_EPS);

            #pragma unroll
            for (int p = 0; p < PPW; ++p) {
                // shared: v1 = p - a  (== reference's dp = a1 - b1)
                float v1x = px[p] - ac.x, v1y = py[p] - ac.y;
                // point-to-segment distance (pad: d=0 -> endpoint distance,
                // >= adjacent real segment's distance -> min unaffected)
                float proj = (v1x * dx + v1y * dy) * inv_e2;
                proj = __builtin_amdgcn_fmed3f(proj, 0.0f, 1.0f);
                float ex = v1x - dx * proj;
                float ey = v1y - dy * proj;
                min_d2[p] = fminf(min_d2[p], ex * ex + ey * ey);
                // intersection, division-free (w = cross(da,db)+EPS):
                //   t,u in [0,1]  <=>  ct*w in [0,w^2] and cu*w in [0,w^2]
                float w  = dax[p] * dy - day[p] * dx + F_EPS;
                float w2 = w * w;
                float ct = (dax[p] * v1y - day[p] * v1x) * w;
                float cu = (dx * v1y - dy * v1x) * w;
                bool inb = (ct >= 0.0f) & (ct <= w2) & (cu >= 0.0f) & (cu <= w2);
                hit[p] |= valid & (int)inb;
            }
        }
    }

    // ---- reduce min_d2 / hit across 64 lanes ----
    #pragma unroll
    for (int off = 1; off <= 32; off <<= 1) {
        #pragma unroll
        for (int p = 0; p < PPW; ++p) {
            min_d2[p] = fminf(min_d2[p], __shfl_xor(min_d2[p], off));
            hit[p]   |= __shfl_xor(hit[p], off);
        }
    }

    // ---- final loss for this wave's 4 points, one atomic per wave ----
    float total = 0.0f;
    #pragma unroll
    for (int p = 0; p < PPW; ++p) {
        float md = sqrtf(min_d2[p]);
        float sd = hit[p] ? md : -md;               // inside -> negative
        total += fmaxf(sd + F_THRESHOLD, 0.0f);
    }
    if (lane == 0)
        atomicAdd(&out[bc], total);
}

extern "C" void kernel_launch(void* const* d_in, const int* in_sizes, int n_in,
                              void* d_out, int out_size, void* d_ws, size_t ws_size,
                              hipStream_t stream) {
    const float* points      = (const float*)d_in[0];
    const float* boundary    = (const float*)d_in[1];
    const float* centerlines = (const float*)d_in[2];
    float* out = (float*)d_out;
    hipMemsetAsync(out, 0, (size_t)out_size * sizeof(float), stream);
    offroad_kernel<<<cB * cC * G, 256, 0, stream>>>(points, boundary, centerlines, out);
}